// Round 1
// 227.789 us; speedup vs baseline: 1.1321x; 1.1321x over previous
//
#include <hip/hip_runtime.h>
#include <hip/hip_fp16.h>

// NNConv on MI355X. msg[E x 32] = Z[E x 4096] @ w2r[4096 x 32],
// Z[e, c*32+i] = h[e,c]*xs[e,i] built on the fly in fp16 A-fragments via
// v_pk_mul_f16. 4 waves x 64 edges.
// Round 11: BARRIER-FREE edge kernel. The only cross-wave state was the
// staged w2 chunk (w2c) -- but every wave reads the full 8 KB chunk anyway,
// and w2p is only 256 KB (L2-resident per XCD). So: read B-fragments
// directly from global into double-buffered registers (half-chunk = 4 frags
// = 16 VGPRs per buffer, prefetch distance 2 half-chunks ~ 8 MFMAs), and
// delete all 32 __syncthreads/vmcnt(0) drains per block. hTq stays
// wave-private LDS (8 KB). L2 w2 traffic rises to ~1.6 GB (~46 us @ 34.5
// TB/s) overlapping the ~42 us MFMA floor.

#define NN 25000
#define EE 400000

typedef _Float16 f16x8 __attribute__((ext_vector_type(8)));
typedef float    f32x16 __attribute__((ext_vector_type(16)));

// ---------------- prep: pack w1/w2/b2 to fp16 fragment layout + zero replicas ----------------
__global__ __launch_bounds__(256) void prep_kernel(
    const float* __restrict__ w1, const float* __restrict__ w2,
    const float* __restrict__ b2,
    _Float16* __restrict__ w2p, _Float16* __restrict__ w1p, _Float16* __restrict__ b2p,
    float4* __restrict__ part4, int nzero4)
{
    int b = blockIdx.x;
    if (b < 532) {                       // 532*256 = 136192 pack threads, exact
        int t = b * 256 + threadIdx.x;
        if (t < 131072) {
            int j = t & 7, lane = (t >> 3) & 63, ih = (t >> 9) & 1, c = t >> 10;
            w2p[t] = (_Float16)w2[c * 1024 + (ih * 16 + ((lane >> 5) << 3) + j) * 32 + (lane & 31)];
        } else if (t < 135168) {
            int u = t - 131072;
            int j = u & 7, lane = (u >> 3) & 63, kk = (u >> 9) & 1, r = u >> 10;
            w1p[u] = (_Float16)w1[(kk * 16 + ((lane >> 5) << 3) + j) * 128 + r * 32 + (lane & 31)];
        } else {
            int u = t - 135168;
            int j = u & 7, lane = (u >> 3) & 63, ih = u >> 9;
            b2p[u] = (_Float16)b2[(ih * 16 + ((lane >> 5) << 3) + j) * 32 + (lane & 31)];
        }
    } else {
        int z = (b - 532) * 256 + threadIdx.x;
        if (z < nzero4) part4[z] = make_float4(0.f, 0.f, 0.f, 0.f);
    }
}

// ---------------- final: out = x@root + bias + sum(replicas) ----------------
__global__ __launch_bounds__(256) void final_kernel(
    const float* __restrict__ x, const float* __restrict__ root,
    const float* __restrict__ bias, const float* __restrict__ part,
    int ncopies, float* __restrict__ out)
{
    int gid = blockIdx.x * 256 + threadIdx.x;   // exactly NN*32
    int n = gid >> 5, o = gid & 31;
    float acc = bias[o];
    const float* xr = x + (n << 5);
#pragma unroll
    for (int i = 0; i < 32; ++i)
        acc = fmaf(xr[i], root[(i << 5) + o], acc);
    for (int c = 0; c < ncopies; ++c) acc += part[(size_t)c * 800000 + gid];
    out[gid] = acc;
}

// ---------------- fused MFMA edge kernel (barrier-free) ----------------
// 256 thr = 4 waves x 64 edges (2 groups of 32) = 256 edges/block, 1563 blocks.
__global__ __launch_bounds__(256, 3) void edge_kernel(
    const float*    __restrict__ x,
    const int*      __restrict__ ei,
    const float*    __restrict__ ea,
    const float*    __restrict__ b1,
    const _Float16* __restrict__ w2p,
    const _Float16* __restrict__ w1p,
    const _Float16* __restrict__ b2p,
    float* __restrict__ outp, int copyMask)
{
    __shared__ unsigned short hTq[4][16][32][2];           // 8 KB: 16-slot split hT (wave-private)

    const int t    = threadIdx.x;
    const int w    = t >> 6;
    const int lane = t & 63;
    const int l    = lane & 31;
    const int half = lane >> 5;

    const int  ebraw = blockIdx.x * 256 + w * 64;
    const bool live  = (ebraw + 64) <= EE;                 // wave-uniform
    const int  ebw   = live ? ebraw : (EE - 64);

    float* __restrict__ myout = outp + (size_t)(blockIdx.x & copyMask) * 800000;

    union u8h { f16x8 v; __half2 h2[4]; };

    // ---- w2 B-fragments read DIRECTLY from global (L2-resident, 256 KB) ----
    // half-chunk hc = 4 fragments (4 KB); fragment fi of hc at
    // f16x8 element index (hc*4 + fi)*64 + lane.
    const f16x8* __restrict__ w2f = (const f16x8*)w2p;

    f16x8 B0[4], B1[4];                                    // double-buffered half-chunks
    auto loadHalf = [&](int hc, f16x8 (&B)[4]) {
        const f16x8* p = w2f + (size_t)hc * 256 + lane;
#pragma unroll
        for (int fi = 0; fi < 4; ++fi) B[fi] = p[fi * 64];
    };
    loadHalf(0, B0);                   // get loads flying before reg setup
    loadHalf(1, B1);

    // ---- persistent edge-attr fragments (fp16), 2 groups; read ONCE ----
    u8h eaf[2][2];
#pragma unroll
    for (int g = 0; g < 2; ++g)
#pragma unroll
        for (int kk = 0; kk < 2; ++kk) {
            const float* p = ea + (ebw + g * 32 + l) * 32 + kk * 16 + half * 8;
            float4 a0 = *(const float4*)p;
            float4 a1 = *(const float4*)(p + 4);
            eaf[g][kk].h2[0] = __float22half2_rn(make_float2(a0.x, a0.y));
            eaf[g][kk].h2[1] = __float22half2_rn(make_float2(a0.z, a0.w));
            eaf[g][kk].h2[2] = __float22half2_rn(make_float2(a1.x, a1.y));
            eaf[g][kk].h2[3] = __float22half2_rn(make_float2(a1.z, a1.w));
        }

    // ---- gather xs rows (fp16 pairs) for 2 groups ----
    __half2 xs0[8], xs1[8];
    {
        int s0 = ei[ebw + l], s1 = ei[ebw + 32 + l];
#pragma unroll
        for (int ih = 0; ih < 2; ++ih) {
            float4 a0 = *(const float4*)(x + s0 * 32 + ih * 16 + half * 8);
            float4 a1 = *(const float4*)(x + s0 * 32 + ih * 16 + half * 8 + 4);
            xs0[ih*4+0] = __float22half2_rn(make_float2(a0.x, a0.y));
            xs0[ih*4+1] = __float22half2_rn(make_float2(a0.z, a0.w));
            xs0[ih*4+2] = __float22half2_rn(make_float2(a1.x, a1.y));
            xs0[ih*4+3] = __float22half2_rn(make_float2(a1.z, a1.w));
            float4 c0 = *(const float4*)(x + s1 * 32 + ih * 16 + half * 8);
            float4 c1 = *(const float4*)(x + s1 * 32 + ih * 16 + half * 8 + 4);
            xs1[ih*4+0] = __float22half2_rn(make_float2(c0.x, c0.y));
            xs1[ih*4+1] = __float22half2_rn(make_float2(c0.z, c0.w));
            xs1[ih*4+2] = __float22half2_rn(make_float2(c1.x, c1.y));
            xs1[ih*4+3] = __float22half2_rn(make_float2(c1.z, c1.w));
        }
    }

    f32x16 acc0, acc1;
#pragma unroll
    for (int i = 0; i < 16; ++i) { acc0[i] = 0.f; acc1[i] = 0.f; }

    unsigned held[8];                        // rows 16-31 of current slice, (g0,g1) packed

    // ---- phase-1 slice for r: rows 0-15 -> hTq slots now, rows 16-31 -> held ----
    auto phase1 = [&](int r) {
        f16x8 w1f0 = *(const f16x8*)(w1p + ((r * 2 + 0) * 64 + lane) * 8);
        f16x8 w1f1 = *(const f16x8*)(w1p + ((r * 2 + 1) * 64 + lane) * 8);
#pragma unroll
        for (int g = 0; g < 2; ++g) {
            f32x16 h;
#pragma unroll
            for (int i = 0; i < 16; ++i) h[i] = 0.f;
            h = __builtin_amdgcn_mfma_f32_32x32x16_f16(w1f0, eaf[g][0].v, h, 0, 0, 0);
            h = __builtin_amdgcn_mfma_f32_32x32x16_f16(w1f1, eaf[g][1].v, h, 0, 0, 0);
#pragma unroll
            for (int i = 0; i < 16; ++i) {
                int row = (i & 3) + ((i >> 2) << 3) + (half << 2);   // verified C/D map
                float hv = fmaxf(h[i] + b1[r * 32 + row], 0.f);
                unsigned short us = __half_as_ushort(__float2half(hv));
                if (i < 8) {
                    hTq[w][row][l][g] = us;                  // rows 0-15: slot == row
                } else {
                    int j = i - 8;                           // rows 16-31: hold in regs
                    if (g == 0) held[j] = us;
                    else        held[j] |= (unsigned)us << 16;
                }
            }
        }
    };

    // writes held rows into slots (wave-private; between chunk q=3 and q=4)
    auto flushHeld = [&]() {
#pragma unroll
        for (int j = 0; j < 8; ++j) {
            int slot = (j & 3) + ((j >> 2) << 3) + (half << 2);   // row-16
            *(unsigned*)&hTq[w][slot][l][0] = held[j];
        }
    };

    // compute one half-chunk (2 c-columns) from register fragments
    auto computeHalf = [&](int q4, int hh, const f16x8 (&B)[4]) {
#pragma unroll
        for (int c2 = 0; c2 < 2; ++c2) {
            const int cl = hh * 2 + c2;
            unsigned u = *(const unsigned*)&hTq[w][(q4 << 2) + cl][l][0];
            __half2 hp = *reinterpret_cast<const __half2*>(&u);
            __half2 h0 = __half2half2(__low2half(hp));       // dup for group 0
            __half2 h1 = __half2half2(__high2half(hp));      // dup for group 1
#pragma unroll
            for (int ih = 0; ih < 2; ++ih) {
                f16x8 bfr = B[c2 * 2 + ih];
                u8h A;
#pragma unroll
                for (int p = 0; p < 4; ++p)
                    A.h2[p] = __hmul2(h0, xs0[ih * 4 + p]);      // v_pk_mul_f16
                acc0 = __builtin_amdgcn_mfma_f32_32x32x16_f16(A.v, bfr, acc0, 0, 0, 0);
#pragma unroll
                for (int p = 0; p < 4; ++p)
                    A.h2[p] = __hmul2(h1, xs1[ih * 4 + p]);
                acc1 = __builtin_amdgcn_mfma_f32_32x32x16_f16(A.v, bfr, acc1, 0, 0, 0);
            }
        }
    };

    // ---- pipeline: no barriers. compute(hc) ; refill freed buffer with hc+2 ----
    phase1(0);
#pragma unroll 1
    for (int r = 0; r < 4; ++r) {
        if (r > 0) phase1(r);              // wave-private hTq: no barrier needed
#pragma unroll
        for (int q = 0; q < 8; ++q) {
            const int cc = r * 8 + q;
            if (q == 4) flushHeld();       // rows 16-31 into the 16 slots
            computeHalf(q & 3, 0, B0);     // hc = 2*cc
            if (cc < 31) loadHalf(cc * 2 + 2, B0);
            computeHalf(q & 3, 1, B1);     // hc = 2*cc+1
            if (cc < 31) loadHalf(cc * 2 + 3, B1);
        }
    }

    // ---- b2 contribution: extra K-step with h == 1 (A-fragment = xs, no VALU) ----
#pragma unroll
    for (int ih = 0; ih < 2; ++ih) {
        f16x8 bfr = *(const f16x8*)(b2p + (ih * 64 + lane) * 8);
        u8h A;
#pragma unroll
        for (int p = 0; p < 4; ++p) A.h2[p] = xs0[ih * 4 + p];
        acc0 = __builtin_amdgcn_mfma_f32_32x32x16_f16(A.v, bfr, acc0, 0, 0, 0);
#pragma unroll
        for (int p = 0; p < 4; ++p) A.h2[p] = xs1[ih * 4 + p];
        acc1 = __builtin_amdgcn_mfma_f32_32x32x16_f16(A.v, bfr, acc1, 0, 0, 0);
    }

    // ---- scatter into this block's replica (skip for clamped tail waves) ----
    if (live) {
#pragma unroll
        for (int i = 0; i < 16; ++i) {
            int el = (i & 3) + ((i >> 2) << 3) + (half << 2);
            atomicAdd(myout + ei[EE + ebw +      el] * 32 + l, acc0[i]);
            atomicAdd(myout + ei[EE + ebw + 32 + el] * 32 + l, acc1[i]);
        }
    }
}

extern "C" void kernel_launch(void* const* d_in, const int* in_sizes, int n_in,
                              void* d_out, int out_size, void* d_ws, size_t ws_size,
                              hipStream_t stream) {
    const float* x    = (const float*)d_in[0];
    const int*   ei   = (const int*)  d_in[1];
    const float* ea   = (const float*)d_in[2];
    const float* w1   = (const float*)d_in[3];
    const float* b1   = (const float*)d_in[4];
    const float* w2   = (const float*)d_in[5];
    const float* b2   = (const float*)d_in[6];
    const float* root = (const float*)d_in[7];
    const float* bias = (const float*)d_in[8];
    float* out = (float*)d_out;

    _Float16* w2p = (_Float16*)d_ws;                      // 262144 B
    _Float16* w1p = (_Float16*)((char*)d_ws + 262144);    //   8192 B
    _Float16* b2p = (_Float16*)((char*)d_ws + 270336);    //   2048 B
    const size_t partOff = 272384;
    const size_t one = 800000ull * sizeof(float);         // 3.2 MB per replica
    size_t avail = (ws_size > partOff) ? ws_size - partOff : 0;
    int nc = 0;
    for (int c = 8; c >= 1; c >>= 1)
        if ((size_t)c * one <= avail) { nc = c; break; }

    float* part = (float*)((char*)d_ws + partOff);
    if (nc > 0) {
        int nzero4 = nc * 200000;                         // float4 count
        int zb = (nzero4 + 255) / 256;
        prep_kernel<<<532 + zb, 256, 0, stream>>>(w1, w2, b2, w2p, w1p, b2p,
                                                  (float4*)part, nzero4);
        edge_kernel<<<(EE + 255) / 256, 256, 0, stream>>>(x, ei, ea, b1, w2p, w1p, b2p,
                                                          part, nc - 1);
        final_kernel<<<(NN * 32) / 256, 256, 0, stream>>>(x, root, bias, part, nc, out);
    } else {
        prep_kernel<<<532, 256, 0, stream>>>(w1, w2, b2, w2p, w1p, b2p, (float4*)part, 0);
        final_kernel<<<(NN * 32) / 256, 256, 0, stream>>>(x, root, bias, part, 0, out);
        edge_kernel<<<(EE + 255) / 256, 256, 0, stream>>>(x, ei, ea, b1, w2p, w1p, b2p,
                                                          out, 0);
    }
}